// Round 2
// baseline (273.431 us; speedup 1.0000x reference)
//
#include <hip/hip_runtime.h>

// LIF recurrence: u_t = decay*u_{t-1} + x_t - o_{t-1}*VTH ; o_t = (u_t - VTH > 0)
// x: [B=64, N=4096, T=100] f32, T contiguous (400 B per neuron row).
//
// R8: no-LDS round. R2-R6 (LDS slab transpose variants) all pinned at
// ~2.47 TB/s, VALUBusy 6%, occupancy 12% -- latency/concurrency-bound by the
// 25.6 KB/wave LDS slab (6 waves/CU). R7 (chunked 5 KB window) failed
// correctness: divergent in-place LDS RMW + rotate raced.
//
// This round deletes LDS entirely and lets the cache hierarchy do the
// transpose:
//   - lane l loads ITS OWN row: 25 x global_load_dwordx4 at 400 B stride,
//     all issued before first use (25.6 KB in flight per wave). Each 64 B
//     line is touched by one lane on 4 consecutive k -> MSHR-merged, fetched
//     from HBM exactly once. HBM read traffic stays ideal (~105 MB).
//   - compute is a pure per-lane register chain (no LDS, no shuffles, no
//     barriers -> no ordering hazards at all). Expression identical to the
//     bit-exact R6 (decay=0.5, o*VTH in {0,0.5} are exact products).
//   - 25 scattered 16 B stores per lane; 4 consecutive k fill each 64 B
//     line, L2 write-combines to full lines. Normal (cached) stores, not NT,
//     so partial-line merging happens in L2 instead of at HBM.
//
// Occupancy: LDS=0, VGPRs ~112 (row lives in 100 VGPRs), capped to 128 by
// __launch_bounds__(64,4) -> grid-limited 16 waves/CU (4/SIMD), ~2.7x the
// R6 residency, with far more bytes in flight per wave.

#define VTH 0.5f
#define T_STEPS 100
#define W 64                   // neurons per block == threads per block (1 wave)
#define K 25                   // float4s per neuron row (100 floats)

typedef float vfloat4 __attribute__((ext_vector_type(4)));

__global__ __launch_bounds__(64, 4) void lif_kernel(const float* __restrict__ x,
                                                    const float* __restrict__ decay_p,
                                                    float* __restrict__ out,
                                                    int n_neurons) {
    const int lane = threadIdx.x;
    const float decay = decay_p[0];

    // This lane's neuron row (25 float4s, contiguous).
    const size_t row_f4 = ((size_t)blockIdx.x * W + lane) * (size_t)K;
    const vfloat4* __restrict__ g4 = (const vfloat4*)x + row_f4;
    vfloat4* __restrict__ o4 = (vfloat4*)out + row_f4;

    // ---- Load: entire row into registers, all 25 loads issued up front.
    vfloat4 r[K];
    #pragma unroll
    for (int k = 0; k < K; ++k) r[k] = g4[k];

    // ---- Compute: serial LIF chain, registers only.
    float u = 0.0f, o = 0.0f;
    #pragma unroll
    for (int k = 0; k < K; ++k) {
        vfloat4 t = r[k];
        u = decay * u + t.x - o * VTH; o = (u > VTH) ? 1.0f : 0.0f; t.x = o;
        u = decay * u + t.y - o * VTH; o = (u > VTH) ? 1.0f : 0.0f; t.y = o;
        u = decay * u + t.z - o * VTH; o = (u > VTH) ? 1.0f : 0.0f; t.z = o;
        u = decay * u + t.w - o * VTH; o = (u > VTH) ? 1.0f : 0.0f; t.w = o;
        r[k] = t;
    }

    // ---- Store: per-lane 16 B stores; consecutive k write-combine into
    // full 64 B lines in L2.
    #pragma unroll
    for (int k = 0; k < K; ++k) o4[k] = r[k];
}

extern "C" void kernel_launch(void* const* d_in, const int* in_sizes, int n_in,
                              void* d_out, int out_size, void* d_ws, size_t ws_size,
                              hipStream_t stream) {
    const float* x = (const float*)d_in[0];
    const float* decay = (const float*)d_in[1];
    float* out = (float*)d_out;

    const int n_neurons = in_sizes[0] / T_STEPS;   // 262,144
    const int grid = n_neurons / W;                // 4096 single-wave blocks

    lif_kernel<<<grid, W, 0, stream>>>(x, decay, out, n_neurons);
}

// Round 3
// 185.735 us; speedup vs baseline: 1.4722x; 1.4722x over previous
//
#include <hip/hip_runtime.h>

// LIF recurrence: u_t = decay*u_{t-1} + x_t - o_{t-1}*VTH ; o_t = (u_t - VTH > 0)
// x: [B=64, N=4096, T=100] f32, T contiguous (400 B per neuron row).
//
// R9: producer/consumer wave specialization.
//   - R6 (best correct: 63.8 us/dispatch): single wave, full 25.6 KB slab,
//     perfect traffic (51 MB fetch w/ L3 absorption, 102 MB full-line writes)
//     but load duty cycle ~20% -> ~7 KB in flight per CU -> 2.4 TB/s.
//   - R8 (no LDS): 2x traffic from partial-line stores + re-fetch. Dead end.
//   - Fix: dedicate wave 1 of a 128-thread block to staging (producer) and
//     wave 0 to compute+store (consumer), double-buffered full slabs.
//     vmcnt is PER-WAVE: the consumer's waits never drain the producer's
//     outstanding loads, so each block keeps ~25.6 KB in flight continuously
//     (~77 KB/CU at 3 blocks/CU) instead of only during a short burst.
//   - Persistent 768-block grid, grid-strided over 4096 slabs; one
//     __syncthreads() per slab for the buffer handoff. No divergent loops,
//     no in-place window rotation (the R7 failure class).
//
// Consumer compute/store phases are copied verbatim from the bit-exact R6:
// same LDS layout, same expression (decay=0.5 and o*VTH in {0,0.5} are exact
// products -> FMA contraction cannot perturb u), same NT full-line stores.

#define VTH 0.5f
#define T_STEPS 100
#define W 64                   // lanes per wave == neurons per slab row-group
#define K 25                   // float4s per neuron row (100 floats)
#define SLAB_F4 (W * K)        // 1600 float4s = 25.6 KB per slab

typedef float vfloat4 __attribute__((ext_vector_type(4)));

__global__ __launch_bounds__(128) void lif_kernel(const float* __restrict__ x,
                                                  const float* __restrict__ decay_p,
                                                  float* __restrict__ out,
                                                  int nslab) {
    __shared__ vfloat4 buf[2][SLAB_F4];   // 51,200 B -> 3 blocks/CU

    const int lane = threadIdx.x & 63;
    const bool producer = threadIdx.x >= W;   // wave 1 stages, wave 0 computes
    const float decay = decay_p[0];

    const int b0 = blockIdx.x;
    const int stride = gridDim.x;
    const int m = (nslab - 1 - b0) / stride + 1;   // slabs for this block

    const vfloat4* __restrict__ x4 = (const vfloat4*)x;
    vfloat4* __restrict__ y4 = (vfloat4*)out;

    // ---- Prologue: producer stages slab 0 into buf[0].
    if (producer) {
        const vfloat4* __restrict__ g = x4 + (size_t)b0 * SLAB_F4;
        vfloat4 v[K];
        #pragma unroll
        for (int k = 0; k < K; ++k) v[k] = g[k * W + lane];
        #pragma unroll
        for (int k = 0; k < K; ++k) buf[0][k * W + lane] = v[k];
    }
    __syncthreads();

    for (int j = 0; j < m; ++j) {
        const int cur = j & 1;

        if (producer) {
            // Stage slab j+1 into the other buffer while the consumer works
            // on buf[cur]. 25 coalesced 1 KB loads all issued up front; the
            // compiler's per-use vmcnt waits let ds_writes land as loads
            // return. Loads stay in flight under the consumer's compute.
            if (j + 1 < m) {
                const vfloat4* __restrict__ g =
                    x4 + ((size_t)b0 + (size_t)(j + 1) * stride) * SLAB_F4;
                vfloat4 v[K];
                #pragma unroll
                for (int k = 0; k < K; ++k) v[k] = g[k * W + lane];
                #pragma unroll
                for (int k = 0; k < K; ++k) buf[cur ^ 1][k * W + lane] = v[k];
            }
        } else {
            // ---- Compute (verbatim R6): lane owns one neuron row; in-place
            // overwrite x -> o inside the slab. Single wave: same-wave DS
            // ordering suffices within this phase.
            vfloat4* __restrict__ bb = buf[cur];
            float u = 0.0f, o = 0.0f;
            #pragma unroll
            for (int i = 0; i < K; ++i) {
                vfloat4 t = bb[lane * K + i];
                u = decay * u + t.x - o * VTH; o = (u > VTH) ? 1.0f : 0.0f; t.x = o;
                u = decay * u + t.y - o * VTH; o = (u > VTH) ? 1.0f : 0.0f; t.y = o;
                u = decay * u + t.z - o * VTH; o = (u > VTH) ? 1.0f : 0.0f; t.z = o;
                u = decay * u + t.w - o * VTH; o = (u > VTH) ? 1.0f : 0.0f; t.w = o;
                bb[lane * K + i] = t;
            }

            // ---- Store (verbatim R6): lane-contiguous LDS reads,
            // line-perfect 1 KB wave-wide non-temporal stores.
            vfloat4* __restrict__ og =
                y4 + ((size_t)b0 + (size_t)j * stride) * SLAB_F4;
            #pragma unroll
            for (int k = 0; k < K; ++k) {
                __builtin_nontemporal_store(bb[k * W + lane], &og[k * W + lane]);
            }
        }

        // Handoff: buf[cur^1] fully staged; consumer done with buf[cur]
        // (safe for the producer to overwrite it next iteration).
        __syncthreads();
    }
}

extern "C" void kernel_launch(void* const* d_in, const int* in_sizes, int n_in,
                              void* d_out, int out_size, void* d_ws, size_t ws_size,
                              hipStream_t stream) {
    const float* x = (const float*)d_in[0];
    const float* decay = (const float*)d_in[1];
    float* out = (float*)d_out;

    const int n_neurons = in_sizes[0] / T_STEPS;   // 262,144
    const int nslab = n_neurons / W;               // 4096 slabs
    const int grid = (nslab < 768) ? nslab : 768;  // 3 blocks/CU (LDS-limited)

    lif_kernel<<<grid, 2 * W, 0, stream>>>(x, decay, out, nslab);
}